// Round 3
// baseline (176.419 us; speedup 1.0000x reference)
//
#include <hip/hip_runtime.h>

#define S_ 512
#define L_ 128
#define D_ 256
#define B_ 128
#define P_ 16
#define H2_ 128
#define F_ 256
#define FEAT_ 640
#define ED_ 64
#define SH_STRIDE 264   // 256 + 8: rows stay 16B-aligned (264*4 % 16 == 0)
#define LP_STRIDE 65    // +1 pad breaks bank alignment for logit partials

// One block per (b, pool). The 2nd block of each b-pair to finish also runs the head.
__global__ __launch_bounds__(256) void fused_kernel(
    const int* __restrict__ x, const int* __restrict__ ents,
    const int* __restrict__ spos, const int* __restrict__ tpos,
    const float* __restrict__ emb, const float* __restrict__ ent_emb,
    const float* __restrict__ attw_W, const float* __restrict__ attw_b,
    const float* __restrict__ attw2_W,
    const float* __restrict__ cond_W, const float* __restrict__ cond_b,
    const float* __restrict__ lin_W, const float* __restrict__ lin_b,
    float* __restrict__ ws_pool, int* __restrict__ counters,
    float* __restrict__ out)
{
    const int bid = blockIdx.x;
    const int b = bid >> 1, pool = bid & 1;
    const int t = threadIdx.x;

    __shared__ float sh[P_ * SH_STRIDE];   // 16 gathered rows, fp32 (16.9 KB)
    __shared__ float lp[P_ * LP_STRIDE];   // logit partials [p][hp] (4.2 KB)
    __shared__ float logits[P_];
    __shared__ float wts[P_];
    __shared__ int   sflag;
    __shared__ float feats[FEAT_];
    __shared__ float r0s[4], r1s[4];

    // ---- gather: 16 threads per row, 4 x float4 each (LDS stores 16B-aligned) ----
    {
        const int* pos = pool ? tpos : spos;
        const int p = t >> 4, i = t & 15;
        const int si  = pos[(b * P_ + p) * 2 + 0];
        const int ti  = pos[(b * P_ + p) * 2 + 1];
        const int tok = x[si * L_ + ti];
        const float4* row = (const float4*)(emb + (size_t)tok * D_);
        float4* dst = (float4*)&sh[p * SH_STRIDE + i * 16];
        #pragma unroll
        for (int j = 0; j < 4; ++j) dst[j] = row[i * 4 + j];
    }
    __syncthreads();

    // ---- energy: thread = (hp = t>>3 in [0,32) -> 4 h rows, dh = t&7 -> d-stripe) ----
    // chunk index cc = 8*c + dh (interleaved stripes: the 8 distinct broadcast
    // addresses per wave land on disjoint bank quads -> conflict-free).
    // Per chunk: 16 LDS b128 reads serve 4 h x 16 p x 4 d = 256 FMAs (h_r=4 reuse).
    {
        const int hp = t >> 3, dh = t & 7;
        const int h0 = hp * 4;
        const float4* W4 = (const float4*)attw_W;   // row = 64 chunks of 4 floats
        float acc[4][P_];
        #pragma unroll
        for (int q = 0; q < 4; ++q)
            #pragma unroll
            for (int p = 0; p < P_; ++p) acc[q][p] = 0.f;

        float4 an[4];
        #pragma unroll
        for (int q = 0; q < 4; ++q) an[q] = W4[(h0 + q) * 64 + dh];

        for (int c = 0; c < 8; ++c) {
            float4 a[4];
            #pragma unroll
            for (int q = 0; q < 4; ++q) a[q] = an[q];
            if (c < 7) {
                #pragma unroll
                for (int q = 0; q < 4; ++q) an[q] = W4[(h0 + q) * 64 + 8 * (c + 1) + dh];
            }
            const int d = (8 * c + dh) * 4;
            #pragma unroll
            for (int p = 0; p < P_; ++p) {
                float4 s = *(const float4*)&sh[p * SH_STRIDE + d];
                #pragma unroll
                for (int q = 0; q < 4; ++q)
                    acc[q][p] += a[q].x * s.x + a[q].y * s.y + a[q].z * s.z + a[q].w * s.w;
            }
        }

        // butterfly over the 8 dh lanes (consecutive): full dots on every lane
        #pragma unroll
        for (int m = 1; m <= 4; m <<= 1) {
            #pragma unroll
            for (int q = 0; q < 4; ++q)
                #pragma unroll
                for (int p = 0; p < P_; ++p)
                    acc[q][p] += __shfl_xor(acc[q][p], m, 64);
        }

        // each dh lane finalizes 2 p's: tanh + attw2 weighting, write logit partial
        const float b0 = attw_b[h0],     b1 = attw_b[h0 + 1];
        const float b2 = attw_b[h0 + 2], b3 = attw_b[h0 + 3];
        const float w0 = attw2_W[h0],     w1 = attw2_W[h0 + 1];
        const float w2 = attw2_W[h0 + 2], w3 = attw2_W[h0 + 3];
        #pragma unroll
        for (int k = 0; k < 2; ++k) {
            const int p = dh * 2 + k;
            float v = tanhf(acc[0][p] + b0) * w0 + tanhf(acc[1][p] + b1) * w1
                    + tanhf(acc[2][p] + b2) * w2 + tanhf(acc[3][p] + b3) * w3;
            lp[p * LP_STRIDE + hp] = v;
        }
    }
    __syncthreads();

    // ---- reduce logit partials over 32 hp groups: t = (p = t>>4, g = t&15) ----
    {
        const int p = t >> 4, g = t & 15;
        float s = lp[p * LP_STRIDE + 2 * g] + lp[p * LP_STRIDE + 2 * g + 1];
        #pragma unroll
        for (int m = 1; m <= 8; m <<= 1) s += __shfl_xor(s, m, 64);
        if (g == 0) logits[p] = s;
    }
    __syncthreads();

    // ---- softmax over P=16 ----
    if (t < P_) {
        float l = logits[t];
        float m = l;
        for (int mm = 8; mm >= 1; mm >>= 1) m = fmaxf(m, __shfl_xor(m, mm, 64));
        float e = expf(l - m);
        float ssum = e;
        for (int mm = 8; mm >= 1; mm >>= 1) ssum += __shfl_xor(ssum, mm, 64);
        wts[t] = e / ssum;
    }
    __syncthreads();

    // ---- weighted pool -> global ws (coalesced) ----
    {
        float acc = 0.f;
        #pragma unroll
        for (int p = 0; p < P_; ++p) acc += wts[p] * sh[p * SH_STRIDE + t];
        ws_pool[(size_t)b * 512 + pool * 256 + t] = acc;
    }

    // ---- pair rendezvous: release own pool, 2nd arriver runs the head ----
    __threadfence();                       // release: pool writes visible at agent scope
    if (t == 0) {
        int old = atomicAdd(&counters[b], 1);
        sflag = (old == 1);
    }
    __syncthreads();
    if (!sflag) return;
    __threadfence();                       // acquire: see partner's pool writes

    // ---- head: feats = [s_pool | t_pool | ent_embs] ----
    feats[t]       = ws_pool[(size_t)b * 512 + t];
    feats[256 + t] = ws_pool[(size_t)b * 512 + 256 + t];
    if (t < 128) {
        const int e = ents[b * 2 + (t >> 6)];
        feats[512 + t] = ent_emb[(size_t)e * ED_ + (t & 63)];
    }
    __syncthreads();

    // condensed[f=t]: 640-dot; feats reads are full-wave broadcasts
    const float4* wrow = (const float4*)(cond_W + (size_t)t * FEAT_);  // 160 chunks
    float acc = cond_b[t];
    float4 nxt = wrow[0];
    for (int c = 0; c < 160; ++c) {
        float4 a = nxt;
        if (c < 159) nxt = wrow[c + 1];
        const float* fp = &feats[c * 4];
        acc += a.x * fp[0] + a.y * fp[1] + a.z * fp[2] + a.w * fp[3];
    }
    const float tv = tanhf(acc);
    float v0 = tv * lin_W[t];
    float v1 = tv * lin_W[256 + t];
    for (int m = 32; m >= 1; m >>= 1) {
        v0 += __shfl_xor(v0, m, 64);
        v1 += __shfl_xor(v1, m, 64);
    }
    if ((t & 63) == 0) { r0s[t >> 6] = v0; r1s[t >> 6] = v1; }
    __syncthreads();
    if (t == 0) {
        out[b * 2 + 0] = r0s[0] + r0s[1] + r0s[2] + r0s[3] + lin_b[0];
        out[b * 2 + 1] = r1s[0] + r1s[1] + r1s[2] + r1s[3] + lin_b[1];
    }
}

extern "C" void kernel_launch(void* const* d_in, const int* in_sizes, int n_in,
                              void* d_out, int out_size, void* d_ws, size_t ws_size,
                              hipStream_t stream)
{
    const int* x     = (const int*)d_in[0];
    const int* ents  = (const int*)d_in[1];
    const int* spos  = (const int*)d_in[2];
    const int* tpos  = (const int*)d_in[3];
    const float* emb     = (const float*)d_in[4];
    const float* ent_emb = (const float*)d_in[5];
    const float* attw_W  = (const float*)d_in[6];
    const float* attw_b  = (const float*)d_in[7];
    const float* attw2_W = (const float*)d_in[8];
    const float* cond_W  = (const float*)d_in[9];
    const float* cond_b  = (const float*)d_in[10];
    const float* lin_W   = (const float*)d_in[11];
    const float* lin_b   = (const float*)d_in[12];
    float* ws_pool = (float*)d_ws;                         // [B][2][256] fp32 = 256 KB
    int* counters  = (int*)((char*)d_ws + 256 * 1024);     // [B] arrival counters
    float* out = (float*)d_out;                            // [B][2] fp32

    hipMemsetAsync(counters, 0, B_ * sizeof(int), stream); // ws is re-poisoned 0xAA
    fused_kernel<<<2 * B_, 256, 0, stream>>>(
        x, ents, spos, tpos, emb, ent_emb, attw_W, attw_b, attw2_W,
        cond_W, cond_b, lin_W, lin_b, ws_pool, counters, out);
}

// Round 4
// 173.767 us; speedup vs baseline: 1.0153x; 1.0153x over previous
//
#include <hip/hip_runtime.h>

#define S_ 512
#define L_ 128
#define D_ 256
#define B_ 128
#define P_ 16
#define H2_ 128
#define F_ 256
#define FEAT_ 640
#define ED_ 64
#define SH_STRIDE 264   // 256 + 8: rows stay 16B-aligned (264*4 % 16 == 0)
#define LP_STRIDE 65    // +1 pad breaks bank alignment for logit partials

// One block per (b, pool). The 2nd block of each b-pair to finish also runs the head.
// grid = 256 = 1 block/CU -> 1 wave/SIMD: VGPR budget is free up to ~512,
// so __launch_bounds__(256, 1) to stop the compiler spilling acc[4][16].
__global__ __launch_bounds__(256, 1) void fused_kernel(
    const int* __restrict__ x, const int* __restrict__ ents,
    const int* __restrict__ spos, const int* __restrict__ tpos,
    const float* __restrict__ emb, const float* __restrict__ ent_emb,
    const float* __restrict__ attw_W, const float* __restrict__ attw_b,
    const float* __restrict__ attw2_W,
    const float* __restrict__ cond_W, const float* __restrict__ cond_b,
    const float* __restrict__ lin_W, const float* __restrict__ lin_b,
    float* __restrict__ ws_pool, int* __restrict__ counters,
    float* __restrict__ out)
{
    const int bid = blockIdx.x;
    const int b = bid >> 1, pool = bid & 1;
    const int t = threadIdx.x;

    __shared__ float sh[P_ * SH_STRIDE];   // 16 gathered rows, fp32 (16.9 KB)
    __shared__ float lp[P_ * LP_STRIDE];   // logit partials [p][hp] (4.2 KB)
    __shared__ float logits[P_];
    __shared__ float wts[P_];
    __shared__ int   sflag;
    __shared__ float feats[FEAT_];
    __shared__ float r0s[4], r1s[4];

    // ---- gather: 16 threads per row, 4 x float4 each ----
    {
        const int* pos = pool ? tpos : spos;
        const int p = t >> 4, i = t & 15;
        const int si  = pos[(b * P_ + p) * 2 + 0];
        const int ti  = pos[(b * P_ + p) * 2 + 1];
        const int tok = x[si * L_ + ti];
        const float4* row = (const float4*)(emb + (size_t)tok * D_);
        float4* dst = (float4*)&sh[p * SH_STRIDE + i * 16];
        #pragma unroll
        for (int j = 0; j < 4; ++j) dst[j] = row[i * 4 + j];
    }
    __syncthreads();

    // ---- energy: thread = (hp = t>>3 -> 4 h rows, dh = t&7 -> 8 d-stripes) ----
    // Per chunk: 16 LDS b128 broadcasts serve 4h x 16p x 4d = 256 FMAs.
    // 128 ds_read_b128 per thread; acc[4][16] = 64 VGPRs, held in registers.
    {
        const int hp = t >> 3, dh = t & 7;
        const int h0 = hp * 4;
        const float4* W4 = (const float4*)attw_W;   // row = 64 float4 chunks
        float acc[4][P_];
        #pragma unroll
        for (int q = 0; q < 4; ++q)
            #pragma unroll
            for (int p = 0; p < P_; ++p) acc[q][p] = 0.f;

        float4 an[4];
        #pragma unroll
        for (int q = 0; q < 4; ++q) an[q] = W4[(h0 + q) * 64 + dh];

        for (int c = 0; c < 8; ++c) {
            float4 a[4];
            #pragma unroll
            for (int q = 0; q < 4; ++q) a[q] = an[q];
            if (c < 7) {
                #pragma unroll
                for (int q = 0; q < 4; ++q) an[q] = W4[(h0 + q) * 64 + 8 * (c + 1) + dh];
            }
            const int d = (8 * c + dh) * 4;
            #pragma unroll
            for (int p = 0; p < P_; ++p) {
                float4 s = *(const float4*)&sh[p * SH_STRIDE + d];
                #pragma unroll
                for (int q = 0; q < 4; ++q)
                    acc[q][p] += a[q].x * s.x + a[q].y * s.y + a[q].z * s.z + a[q].w * s.w;
            }
        }

        // butterfly over the 8 dh lanes: full dots on every lane
        #pragma unroll
        for (int m = 1; m <= 4; m <<= 1) {
            #pragma unroll
            for (int q = 0; q < 4; ++q)
                #pragma unroll
                for (int p = 0; p < P_; ++p)
                    acc[q][p] += __shfl_xor(acc[q][p], m, 64);
        }

        const float b0 = attw_b[h0],     b1 = attw_b[h0 + 1];
        const float b2 = attw_b[h0 + 2], b3 = attw_b[h0 + 3];
        const float w0 = attw2_W[h0],     w1 = attw2_W[h0 + 1];
        const float w2 = attw2_W[h0 + 2], w3 = attw2_W[h0 + 3];
        #pragma unroll
        for (int k = 0; k < 2; ++k) {
            const int p = dh * 2 + k;
            float v = tanhf(acc[0][p] + b0) * w0 + tanhf(acc[1][p] + b1) * w1
                    + tanhf(acc[2][p] + b2) * w2 + tanhf(acc[3][p] + b3) * w3;
            lp[p * LP_STRIDE + hp] = v;
        }
    }
    __syncthreads();

    // ---- reduce logit partials over 32 hp groups: t = (p = t>>4, g = t&15) ----
    {
        const int p = t >> 4, g = t & 15;
        float s = lp[p * LP_STRIDE + 2 * g] + lp[p * LP_STRIDE + 2 * g + 1];
        #pragma unroll
        for (int m = 1; m <= 8; m <<= 1) s += __shfl_xor(s, m, 64);
        if (g == 0) logits[p] = s;
    }
    __syncthreads();

    // ---- softmax over P=16 ----
    if (t < P_) {
        float l = logits[t];
        float m = l;
        for (int mm = 8; mm >= 1; mm >>= 1) m = fmaxf(m, __shfl_xor(m, mm, 64));
        float e = expf(l - m);
        float ssum = e;
        for (int mm = 8; mm >= 1; mm >>= 1) ssum += __shfl_xor(ssum, mm, 64);
        wts[t] = e / ssum;
    }
    __syncthreads();

    // ---- weighted pool -> global ws (coalesced) ----
    {
        float acc = 0.f;
        #pragma unroll
        for (int p = 0; p < P_; ++p) acc += wts[p] * sh[p * SH_STRIDE + t];
        ws_pool[(size_t)b * 512 + pool * 256 + t] = acc;
    }

    // ---- pair rendezvous: release own pool, 2nd arriver runs the head ----
    __threadfence();                       // release
    if (t == 0) {
        int old = atomicAdd(&counters[b], 1);
        sflag = (old == 1);
    }
    __syncthreads();
    if (!sflag) return;
    __threadfence();                       // acquire

    // ---- head: feats = [s_pool | t_pool | ent_embs] ----
    feats[t]       = ws_pool[(size_t)b * 512 + t];
    feats[256 + t] = ws_pool[(size_t)b * 512 + 256 + t];
    if (t < 128) {
        const int e = ents[b * 2 + (t >> 6)];
        feats[512 + t] = ent_emb[(size_t)e * ED_ + (t & 63)];
    }
    __syncthreads();

    // condensed[f=t]: 640-dot, 8-deep software pipeline (8 loads in flight)
    {
        const float4* wrow = (const float4*)(cond_W + (size_t)t * FEAT_);  // 160 chunks
        float acc = cond_b[t];
        float4 buf[8];
        #pragma unroll
        for (int j = 0; j < 8; ++j) buf[j] = wrow[j];
        for (int c = 0; c < 160; c += 8) {
            float4 cur[8];
            #pragma unroll
            for (int j = 0; j < 8; ++j) cur[j] = buf[j];
            if (c + 8 < 160) {
                #pragma unroll
                for (int j = 0; j < 8; ++j) buf[j] = wrow[c + 8 + j];
            }
            #pragma unroll
            for (int j = 0; j < 8; ++j) {
                const float* fp = &feats[(c + j) * 4];
                acc += cur[j].x * fp[0] + cur[j].y * fp[1]
                     + cur[j].z * fp[2] + cur[j].w * fp[3];
            }
        }
        const float tv = tanhf(acc);
        float v0 = tv * lin_W[t];
        float v1 = tv * lin_W[256 + t];
        #pragma unroll
        for (int m = 32; m >= 1; m >>= 1) {
            v0 += __shfl_xor(v0, m, 64);
            v1 += __shfl_xor(v1, m, 64);
        }
        if ((t & 63) == 0) { r0s[t >> 6] = v0; r1s[t >> 6] = v1; }
    }
    __syncthreads();
    if (t == 0) {
        out[b * 2 + 0] = r0s[0] + r0s[1] + r0s[2] + r0s[3] + lin_b[0];
        out[b * 2 + 1] = r1s[0] + r1s[1] + r1s[2] + r1s[3] + lin_b[1];
    }
}

extern "C" void kernel_launch(void* const* d_in, const int* in_sizes, int n_in,
                              void* d_out, int out_size, void* d_ws, size_t ws_size,
                              hipStream_t stream)
{
    const int* x     = (const int*)d_in[0];
    const int* ents  = (const int*)d_in[1];
    const int* spos  = (const int*)d_in[2];
    const int* tpos  = (const int*)d_in[3];
    const float* emb     = (const float*)d_in[4];
    const float* ent_emb = (const float*)d_in[5];
    const float* attw_W  = (const float*)d_in[6];
    const float* attw_b  = (const float*)d_in[7];
    const float* attw2_W = (const float*)d_in[8];
    const float* cond_W  = (const float*)d_in[9];
    const float* cond_b  = (const float*)d_in[10];
    const float* lin_W   = (const float*)d_in[11];
    const float* lin_b   = (const float*)d_in[12];
    float* ws_pool = (float*)d_ws;                         // [B][2][256] fp32 = 256 KB
    int* counters  = (int*)((char*)d_ws + 256 * 1024);     // [B] arrival counters
    float* out = (float*)d_out;                            // [B][2] fp32

    hipMemsetAsync(counters, 0, B_ * sizeof(int), stream); // ws is re-poisoned 0xAA
    fused_kernel<<<2 * B_, 256, 0, stream>>>(
        x, ents, spos, tpos, emb, ent_emb, attw_W, attw_b, attw2_W,
        cond_W, cond_b, lin_W, lin_b, ws_pool, counters, out);
}

// Round 5
// 137.996 us; speedup vs baseline: 1.2784x; 1.2592x over previous
//
#include <hip/hip_runtime.h>

#define S_ 512
#define L_ 128
#define D_ 256
#define B_ 128
#define P_ 16
#define H2_ 128
#define F_ 256
#define FEAT_ 640
#define ED_ 64
#define SH_STRIDE 264   // 256+8: rows 16B-aligned (264*4 % 16 == 0), banks spread
#define LP_STRIDE 33

// grid = B (128 blocks), 512 threads: threads 0-255 = s-pool, 256-511 = t-pool.
// Everything block-local (LDS); no inter-block fences (XCD L2-invalidate trap),
// no workspace. NO dynamic indexing into register arrays (scratch-spill trap).
__global__ __launch_bounds__(512) void fused_kernel(
    const int* __restrict__ x, const int* __restrict__ ents,
    const int* __restrict__ spos, const int* __restrict__ tpos,
    const float* __restrict__ emb, const float* __restrict__ ent_emb,
    const float* __restrict__ attw_W, const float* __restrict__ attw_b,
    const float* __restrict__ attw2_W,
    const float* __restrict__ cond_W, const float* __restrict__ cond_b,
    const float* __restrict__ lin_W, const float* __restrict__ lin_b,
    float* __restrict__ out)
{
    const int b = blockIdx.x;
    const int t = threadIdx.x;
    const int pool = t >> 8;          // wave-uniform
    const int tl = t & 255;

    __shared__ float sh[2 * P_ * SH_STRIDE];     // 33.8 KB: both pools' 16 rows
    __shared__ float lp[2 * P_ * LP_STRIDE];     // logit partials [pool][p][hp]
    __shared__ float logits[32];
    __shared__ float wts[32];
    __shared__ float feats[FEAT_];
    __shared__ float part0[F_], part1[F_];
    __shared__ float r0s[4], r1s[4];

    const int pool_off = pool * P_ * SH_STRIDE;

    // ---- gather: per half, 16 threads per row, 4 x float4 each ----
    {
        const int* pos = pool ? tpos : spos;
        const int p = tl >> 4, i = tl & 15;
        const int si  = pos[(b * P_ + p) * 2 + 0];
        const int ti  = pos[(b * P_ + p) * 2 + 1];
        const int tok = x[si * L_ + ti];
        const float4* row = (const float4*)(emb + (size_t)tok * D_);
        float4* dst = (float4*)&sh[pool_off + p * SH_STRIDE + i * 16];
        #pragma unroll
        for (int j = 0; j < 4; ++j) dst[j] = row[i * 4 + j];
    }
    __syncthreads();

    // ---- energy: per half, thread = (hp = tl>>3 -> 4 h rows, dh = tl&7 -> d-stripe)
    // Two passes over p (8 each): acc[4][8] = 32 VGPRs, no spill.
    // Exchange-reduce over the 8 dh lanes ends with lane dh owning p = dh (all
    // register indices STATIC).
    {
        const int hp = tl >> 3, dh = tl & 7;
        const int h0 = hp * 4;
        const float4* W4 = (const float4*)attw_W;   // 64 float4 per row
        float bq0 = attw_b[h0],     bq1 = attw_b[h0 + 1];
        float bq2 = attw_b[h0 + 2], bq3 = attw_b[h0 + 3];
        float wq0 = attw2_W[h0],     wq1 = attw2_W[h0 + 1];
        float wq2 = attw2_W[h0 + 2], wq3 = attw2_W[h0 + 3];

        #pragma unroll
        for (int pass = 0; pass < 2; ++pass) {
            const int pb = pass * 8;
            float acc[4][8];
            #pragma unroll
            for (int q = 0; q < 4; ++q)
                #pragma unroll
                for (int p = 0; p < 8; ++p) acc[q][p] = 0.f;

            float4 nxt[4];
            #pragma unroll
            for (int q = 0; q < 4; ++q) nxt[q] = W4[(h0 + q) * 64 + dh];

            for (int c = 0; c < 8; ++c) {
                float4 a[4];
                #pragma unroll
                for (int q = 0; q < 4; ++q) a[q] = nxt[q];
                if (c < 7) {
                    #pragma unroll
                    for (int q = 0; q < 4; ++q)
                        nxt[q] = W4[(h0 + q) * 64 + 8 * (c + 1) + dh];
                }
                const int d = (8 * c + dh) * 4;   // 8 distinct b128 addrs/wave: conflict-free
                #pragma unroll
                for (int p = 0; p < 8; ++p) {
                    float4 s = *(const float4*)&sh[pool_off + (pb + p) * SH_STRIDE + d];
                    #pragma unroll
                    for (int q = 0; q < 4; ++q)
                        acc[q][p] += a[q].x * s.x + a[q].y * s.y + a[q].z * s.z + a[q].w * s.w;
                }
            }

            // exchange-reduce: mask 4, then 2, then 1; keep hi/lo half by dh bit
            #pragma unroll
            for (int q = 0; q < 4; ++q) {
                #pragma unroll
                for (int j = 0; j < 4; ++j) {
                    float lo = acc[q][j],     olo = __shfl_xor(lo, 4, 64);
                    float hi = acc[q][j + 4], ohi = __shfl_xor(hi, 4, 64);
                    acc[q][j] = (dh & 4) ? (hi + ohi) : (lo + olo);
                }
                #pragma unroll
                for (int j = 0; j < 2; ++j) {
                    float lo = acc[q][j],     olo = __shfl_xor(lo, 2, 64);
                    float hi = acc[q][j + 2], ohi = __shfl_xor(hi, 2, 64);
                    acc[q][j] = (dh & 2) ? (hi + ohi) : (lo + olo);
                }
                {
                    float lo = acc[q][0], olo = __shfl_xor(lo, 1, 64);
                    float hi = acc[q][1], ohi = __shfl_xor(hi, 1, 64);
                    acc[q][0] = (dh & 1) ? (hi + ohi) : (lo + olo);
                }
            }
            // lane dh now owns the full dot for p = pb + dh, rows h0..h0+3
            float v = tanhf(acc[0][0] + bq0) * wq0 + tanhf(acc[1][0] + bq1) * wq1
                    + tanhf(acc[2][0] + bq2) * wq2 + tanhf(acc[3][0] + bq3) * wq3;
            lp[pool * P_ * LP_STRIDE + (pb + dh) * LP_STRIDE + hp] = v;
        }
    }
    __syncthreads();

    // ---- logit reduce over 32 hp: per half, tl = (p = tl>>4, g = tl&15) ----
    {
        const int p = tl >> 4, g = tl & 15;
        const float* l = &lp[pool * P_ * LP_STRIDE + p * LP_STRIDE];
        float s = l[2 * g] + l[2 * g + 1];
        #pragma unroll
        for (int m = 1; m <= 8; m <<= 1) s += __shfl_xor(s, m, 64);
        if (g == 0) logits[pool * 16 + p] = s;
    }
    __syncthreads();

    // ---- softmax over P=16 per half (lanes 0..15 of wave 0 / wave 4) ----
    if (tl < 16) {
        float l = logits[pool * 16 + tl];
        float m = l;
        for (int mm = 8; mm >= 1; mm >>= 1) m = fmaxf(m, __shfl_xor(m, mm, 64));
        float e = expf(l - m);
        float ssum = e;
        for (int mm = 8; mm >= 1; mm >>= 1) ssum += __shfl_xor(ssum, mm, 64);
        wts[pool * 16 + tl] = e / ssum;
    }
    __syncthreads();

    // ---- weighted pool straight into feats (LDS), plus entity embeddings ----
    {
        float acc = 0.f;
        #pragma unroll
        for (int p = 0; p < P_; ++p)
            acc += wts[pool * 16 + p] * sh[pool_off + p * SH_STRIDE + tl];
        feats[pool * 256 + tl] = acc;
    }
    if (t < 128) {
        const int e = ents[b * 2 + (t >> 6)];
        feats[512 + t] = ent_emb[(size_t)e * ED_ + (t & 63)];
    }
    __syncthreads();

    // ---- head: condensed[f] split in two 320-dim half-dots across the halves ----
    {
        const int f = tl;
        const int cbase = pool ? 80 : 0;
        const float4* wrow = (const float4*)(cond_W + (size_t)f * FEAT_) + cbase;
        float acc = pool ? 0.f : cond_b[f];
        float4 buf[8];
        #pragma unroll
        for (int j = 0; j < 8; ++j) buf[j] = wrow[j];
        for (int c = 0; c < 80; c += 8) {
            float4 cur[8];
            #pragma unroll
            for (int j = 0; j < 8; ++j) cur[j] = buf[j];
            if (c + 8 < 80) {
                #pragma unroll
                for (int j = 0; j < 8; ++j) buf[j] = wrow[c + 8 + j];
            }
            #pragma unroll
            for (int j = 0; j < 8; ++j) {
                const float* fp = &feats[(cbase + c + j) * 4];
                acc += cur[j].x * fp[0] + cur[j].y * fp[1]
                     + cur[j].z * fp[2] + cur[j].w * fp[3];
            }
        }
        if (pool) part1[f] = acc; else part0[f] = acc;
    }
    __syncthreads();

    // ---- tanh + linear head (threads 0..255) ----
    if (t < 256) {
        const float tv = tanhf(part0[t] + part1[t]);
        float v0 = tv * lin_W[t];
        float v1 = tv * lin_W[256 + t];
        #pragma unroll
        for (int m = 32; m >= 1; m >>= 1) {
            v0 += __shfl_xor(v0, m, 64);
            v1 += __shfl_xor(v1, m, 64);
        }
        if ((t & 63) == 0) { r0s[t >> 6] = v0; r1s[t >> 6] = v1; }
    }
    __syncthreads();
    if (t == 0) {
        out[b * 2 + 0] = r0s[0] + r0s[1] + r0s[2] + r0s[3] + lin_b[0];
        out[b * 2 + 1] = r1s[0] + r1s[1] + r1s[2] + r1s[3] + lin_b[1];
    }
}

extern "C" void kernel_launch(void* const* d_in, const int* in_sizes, int n_in,
                              void* d_out, int out_size, void* d_ws, size_t ws_size,
                              hipStream_t stream)
{
    const int* x     = (const int*)d_in[0];
    const int* ents  = (const int*)d_in[1];
    const int* spos  = (const int*)d_in[2];
    const int* tpos  = (const int*)d_in[3];
    const float* emb     = (const float*)d_in[4];
    const float* ent_emb = (const float*)d_in[5];
    const float* attw_W  = (const float*)d_in[6];
    const float* attw_b  = (const float*)d_in[7];
    const float* attw2_W = (const float*)d_in[8];
    const float* cond_W  = (const float*)d_in[9];
    const float* cond_b  = (const float*)d_in[10];
    const float* lin_W   = (const float*)d_in[11];
    const float* lin_b   = (const float*)d_in[12];
    float* out = (float*)d_out;   // [B][2] fp32

    fused_kernel<<<B_, 512, 0, stream>>>(
        x, ents, spos, tpos, emb, ent_emb, attw_W, attw_b, attw2_W,
        cond_W, cond_b, lin_W, lin_b, out);
}

// Round 6
// 123.958 us; speedup vs baseline: 1.4232x; 1.1132x over previous
//
#include <hip/hip_runtime.h>

#define S_ 512
#define L_ 128
#define D_ 256
#define B_ 128
#define P_ 16
#define H2_ 128
#define F_ 256
#define FEAT_ 640
#define ED_ 64
#define SH_STRIDE 264   // 256+8: rows 16B-aligned, banks spread
#define LP_STRIDE 33

// grid = B (128 blocks) x 1024 threads (16 waves/CU for latency hiding).
// All VMEM patterns coalesced (<=16 lines per wave-instr). Block-local only:
// no fences, no workspace, no dynamic register indexing.
__global__ __launch_bounds__(1024) void fused_kernel(
    const int* __restrict__ x, const int* __restrict__ ents,
    const int* __restrict__ spos, const int* __restrict__ tpos,
    const float* __restrict__ emb, const float* __restrict__ ent_emb,
    const float* __restrict__ attw_W, const float* __restrict__ attw_b,
    const float* __restrict__ attw2_W,
    const float* __restrict__ cond_W, const float* __restrict__ cond_b,
    const float* __restrict__ lin_W, const float* __restrict__ lin_b,
    float* __restrict__ out)
{
    const int b = blockIdx.x;
    const int t = threadIdx.x;

    __shared__ float sh[2 * P_ * SH_STRIDE];     // both pools' 16 rows (33.8 KB)
    __shared__ float lp[2 * P_ * LP_STRIDE];     // logit partials [pool][p][hp]
    __shared__ float logits[32];
    __shared__ float wts[32];
    __shared__ float feats[FEAT_];
    __shared__ float part[F_];
    __shared__ float r0s[4], r1s[4];

    // ---- gather: 32 rows total; row r = t>>5, lane sub = t&31 reads float4
    // idx {sub, sub+32} -> per wave-instr: 2 rows x 512 B contiguous. ----
    {
        const int r = t >> 5, sub = t & 31;
        const int pool = r >> 4, p = r & 15;
        const int* pos = pool ? tpos : spos;
        const int si  = pos[(b * P_ + p) * 2 + 0];
        const int ti  = pos[(b * P_ + p) * 2 + 1];
        const int tok = x[si * L_ + ti];
        const float4* row = (const float4*)(emb + (size_t)tok * D_);
        float* base = &sh[pool * P_ * SH_STRIDE + p * SH_STRIDE];
        float4 v0 = row[sub];
        float4 v1 = row[sub + 32];
        *(float4*)&base[sub * 4]        = v0;
        *(float4*)&base[128 + sub * 4]  = v1;
    }
    __syncthreads();

    // ---- energy: 4 quadrants of 256 threads = (pool = q&1, p-group = q>>1).
    // Within quadrant: hp = tl>>3 (4 h-rows), dh = tl&7 (d-stripe).
    // acc[4][8] = 32 VGPRs, static indices only; exchange-reduce over 8 dh
    // lanes leaves lane dh owning p = pb + dh. ----
    {
        const int q2 = t >> 8, tl = t & 255;
        const int pool = q2 & 1, pb = (q2 >> 1) * 8;
        const int pool_off = pool * P_ * SH_STRIDE;
        const int hp = tl >> 3, dh = tl & 7;
        const int h0 = hp * 4;
        const float4* W4 = (const float4*)attw_W;   // 64 float4 per h-row

        float acc[4][8];
        #pragma unroll
        for (int qq = 0; qq < 4; ++qq)
            #pragma unroll
            for (int p = 0; p < 8; ++p) acc[qq][p] = 0.f;

        float4 nxt[4];
        #pragma unroll
        for (int qq = 0; qq < 4; ++qq) nxt[qq] = W4[(h0 + qq) * 64 + dh];

        for (int c = 0; c < 8; ++c) {
            float4 a[4];
            #pragma unroll
            for (int qq = 0; qq < 4; ++qq) a[qq] = nxt[qq];
            if (c < 7) {
                #pragma unroll
                for (int qq = 0; qq < 4; ++qq)
                    nxt[qq] = W4[(h0 + qq) * 64 + 8 * (c + 1) + dh];
            }
            const int d = (8 * c + dh) * 4;   // 8 distinct b128 addrs/wave: conflict-free
            #pragma unroll
            for (int p = 0; p < 8; ++p) {
                float4 s = *(const float4*)&sh[pool_off + (pb + p) * SH_STRIDE + d];
                #pragma unroll
                for (int qq = 0; qq < 4; ++qq)
                    acc[qq][p] += a[qq].x * s.x + a[qq].y * s.y + a[qq].z * s.z + a[qq].w * s.w;
            }
        }

        // exchange-reduce: mask 4, 2, 1; keep hi/lo half by dh bit (all static)
        #pragma unroll
        for (int qq = 0; qq < 4; ++qq) {
            #pragma unroll
            for (int j = 0; j < 4; ++j) {
                float lo = acc[qq][j],     olo = __shfl_xor(lo, 4, 64);
                float hi = acc[qq][j + 4], ohi = __shfl_xor(hi, 4, 64);
                acc[qq][j] = (dh & 4) ? (hi + ohi) : (lo + olo);
            }
            #pragma unroll
            for (int j = 0; j < 2; ++j) {
                float lo = acc[qq][j],     olo = __shfl_xor(lo, 2, 64);
                float hi = acc[qq][j + 2], ohi = __shfl_xor(hi, 2, 64);
                acc[qq][j] = (dh & 2) ? (hi + ohi) : (lo + olo);
            }
            {
                float lo = acc[qq][0], olo = __shfl_xor(lo, 1, 64);
                float hi = acc[qq][1], ohi = __shfl_xor(hi, 1, 64);
                acc[qq][0] = (dh & 1) ? (hi + ohi) : (lo + olo);
            }
        }
        const float b0 = attw_b[h0],     b1 = attw_b[h0 + 1];
        const float b2 = attw_b[h0 + 2], b3 = attw_b[h0 + 3];
        const float w0 = attw2_W[h0],     w1 = attw2_W[h0 + 1];
        const float w2 = attw2_W[h0 + 2], w3 = attw2_W[h0 + 3];
        float v = tanhf(acc[0][0] + b0) * w0 + tanhf(acc[1][0] + b1) * w1
                + tanhf(acc[2][0] + b2) * w2 + tanhf(acc[3][0] + b3) * w3;
        lp[pool * P_ * LP_STRIDE + (pb + dh) * LP_STRIDE + hp] = v;
    }
    __syncthreads();

    // ---- logit reduce over 32 hp: t < 512 = (pool, p, g=t&15) ----
    if (t < 512) {
        const int pool = t >> 8, p = (t >> 4) & 15, g = t & 15;
        const float* l = &lp[pool * P_ * LP_STRIDE + p * LP_STRIDE];
        float s = l[2 * g] + l[2 * g + 1];
        #pragma unroll
        for (int m = 1; m <= 8; m <<= 1) s += __shfl_xor(s, m, 64);
        if (g == 0) logits[pool * 16 + p] = s;
    }
    __syncthreads();

    // ---- softmax over P=16 per pool (lanes 0..15 pool0, 16..31 pool1) ----
    if (t < 32) {
        float l = logits[t];
        float m = l;
        for (int mm = 8; mm >= 1; mm >>= 1) m = fmaxf(m, __shfl_xor(m, mm, 64));
        float e = expf(l - m);
        float ssum = e;
        for (int mm = 8; mm >= 1; mm >>= 1) ssum += __shfl_xor(ssum, mm, 64);
        wts[t] = e / ssum;
    }
    __syncthreads();

    // ---- weighted pool -> feats; entity embeddings -> feats[512:640] ----
    if (t < 512) {
        const int pool = t >> 8, d = t & 255;
        const int pool_off = pool * P_ * SH_STRIDE;
        float acc = 0.f;
        #pragma unroll
        for (int p = 0; p < P_; ++p)
            acc += wts[pool * 16 + p] * sh[pool_off + p * SH_STRIDE + d];
        feats[pool * 256 + d] = acc;
    } else if (t < 640) {
        const int i = t - 512;
        const int e = ents[b * 2 + (i >> 6)];
        feats[512 + i] = ent_emb[(size_t)e * ED_ + (i & 63)];
    }
    __syncthreads();

    // ---- head: condensed[r] for r = g + 64k; 16 lanes split K per row.
    // Per wave-instr: 4 rows x 256 B contiguous chunks (16 lines vs 64). ----
    {
        const int g = t >> 4, sub = t & 15;   // 64 groups x 16 lanes
        #pragma unroll
        for (int k = 0; k < 4; ++k) {
            const int r = g + 64 * k;
            const float4* wrow = (const float4*)(cond_W + (size_t)r * FEAT_);
            float4 w[10];
            #pragma unroll
            for (int j = 0; j < 10; ++j) w[j] = wrow[j * 16 + sub];  // all in flight
            float acc = 0.f;
            #pragma unroll
            for (int j = 0; j < 10; ++j) {
                const float* fp = &feats[(j * 16 + sub) * 4];
                acc += w[j].x * fp[0] + w[j].y * fp[1] + w[j].z * fp[2] + w[j].w * fp[3];
            }
            #pragma unroll
            for (int m = 1; m <= 8; m <<= 1) acc += __shfl_xor(acc, m, 64);
            if (sub == 0) part[r] = acc + cond_b[r];
        }
    }
    __syncthreads();

    // ---- tanh + linear head (threads 0..255) ----
    if (t < 256) {
        const float tv = tanhf(part[t]);
        float v0 = tv * lin_W[t];
        float v1 = tv * lin_W[256 + t];
        #pragma unroll
        for (int m = 32; m >= 1; m >>= 1) {
            v0 += __shfl_xor(v0, m, 64);
            v1 += __shfl_xor(v1, m, 64);
        }
        if ((t & 63) == 0) { r0s[t >> 6] = v0; r1s[t >> 6] = v1; }
    }
    __syncthreads();
    if (t == 0) {
        out[b * 2 + 0] = r0s[0] + r0s[1] + r0s[2] + r0s[3] + lin_b[0];
        out[b * 2 + 1] = r1s[0] + r1s[1] + r1s[2] + r1s[3] + lin_b[1];
    }
}

extern "C" void kernel_launch(void* const* d_in, const int* in_sizes, int n_in,
                              void* d_out, int out_size, void* d_ws, size_t ws_size,
                              hipStream_t stream)
{
    const int* x     = (const int*)d_in[0];
    const int* ents  = (const int*)d_in[1];
    const int* spos  = (const int*)d_in[2];
    const int* tpos  = (const int*)d_in[3];
    const float* emb     = (const float*)d_in[4];
    const float* ent_emb = (const float*)d_in[5];
    const float* attw_W  = (const float*)d_in[6];
    const float* attw_b  = (const float*)d_in[7];
    const float* attw2_W = (const float*)d_in[8];
    const float* cond_W  = (const float*)d_in[9];
    const float* cond_b  = (const float*)d_in[10];
    const float* lin_W   = (const float*)d_in[11];
    const float* lin_b   = (const float*)d_in[12];
    float* out = (float*)d_out;   // [B][2] fp32

    fused_kernel<<<B_, 1024, 0, stream>>>(
        x, ents, spos, tpos, emb, ent_emb, attw_W, attw_b, attw2_W,
        cond_W, cond_b, lin_W, lin_b, out);
}

// Round 7
// 123.627 us; speedup vs baseline: 1.4270x; 1.0027x over previous
//
#include <hip/hip_runtime.h>

#define S_ 512
#define L_ 128
#define D_ 256
#define B_ 128
#define P_ 16
#define H2_ 128
#define F_ 256
#define FEAT_ 640
#define ED_ 64
#define SH_STRIDE 264   // 256+8: rows 16B-aligned, banks spread
#define LP_STRIDE 33

// Cross-block state in device globals: NOT harness-poisoned (d_ws poison fill
// would serialize 42us in front of the kernel), zeroed at module load, and
// gcount self-resets each call (graph-capture safe).
__device__ float gpool[B_][2][D_];
__device__ int   gcount[B_];

// grid = 256 = one block per (b, pool) -> ALL 256 CUs run gather+energy.
// Pair rendezvous is fence-free: publish via atomicExch (device coherent
// point), order the arrival atomicAdd behind exch completion with a
// volatile-LDS data dependency, winner re-reads both pools via atomicAdd(,0).
// Loser exits; winner (2nd arriver) runs the head. No spin, no deadlock.
__global__ __launch_bounds__(512) void fused_kernel(
    const int* __restrict__ x, const int* __restrict__ ents,
    const int* __restrict__ spos, const int* __restrict__ tpos,
    const float* __restrict__ emb, const float* __restrict__ ent_emb,
    const float* __restrict__ attw_W, const float* __restrict__ attw_b,
    const float* __restrict__ attw2_W,
    const float* __restrict__ cond_W, const float* __restrict__ cond_b,
    const float* __restrict__ lin_W, const float* __restrict__ lin_b,
    float* __restrict__ out)
{
    const int bid = blockIdx.x;
    const int b = bid >> 1, pool = bid & 1;
    const int t = threadIdx.x;

    __shared__ float sh[P_ * SH_STRIDE];     // 16 gathered rows (16.9 KB)
    __shared__ float lp[P_ * LP_STRIDE];     // logit partials [p][hp]
    __shared__ float logits[P_];
    __shared__ float wts[P_];
    volatile __shared__ float vdummy[256];   // exch-return sink (ordering)
    __shared__ int sflag;
    __shared__ float feats[FEAT_];
    __shared__ float part[F_];
    __shared__ float r0s[4], r1s[4];

    // ---- gather: 16 rows x 32 lanes, 2 float4 each (2 rows/wave-instr,
    // 512 B contiguous per row half -> 16 lines/instr) ----
    {
        const int r = t >> 5, sub = t & 31;
        const int* pos = pool ? tpos : spos;
        const int si  = pos[(b * P_ + r) * 2 + 0];
        const int ti  = pos[(b * P_ + r) * 2 + 1];
        const int tok = x[si * L_ + ti];
        const float4* row = (const float4*)(emb + (size_t)tok * D_);
        float4 v0 = row[sub];
        float4 v1 = row[sub + 32];
        float* base = &sh[r * SH_STRIDE];
        *(float4*)&base[sub * 4]       = v0;
        *(float4*)&base[128 + sub * 4] = v1;
    }
    __syncthreads();

    // ---- energy: 2 halves of 256 threads = p-group pb in {0,8}.
    // Within half: hp = tl>>3 (4 h-rows), dh = tl&7 (d-stripe).
    // acc[4][8] = 32 VGPRs, static indices; exchange-reduce over 8 dh lanes
    // leaves lane dh owning p = pb + dh. ----
    {
        const int pb = (t >> 8) * 8, tl = t & 255;
        const int hp = tl >> 3, dh = tl & 7;
        const int h0 = hp * 4;
        const float4* W4 = (const float4*)attw_W;   // 64 float4 per h-row

        float acc[4][8];
        #pragma unroll
        for (int qq = 0; qq < 4; ++qq)
            #pragma unroll
            for (int p = 0; p < 8; ++p) acc[qq][p] = 0.f;

        float4 nxt[4];
        #pragma unroll
        for (int qq = 0; qq < 4; ++qq) nxt[qq] = W4[(h0 + qq) * 64 + dh];

        for (int c = 0; c < 8; ++c) {
            float4 a[4];
            #pragma unroll
            for (int qq = 0; qq < 4; ++qq) a[qq] = nxt[qq];
            if (c < 7) {
                #pragma unroll
                for (int qq = 0; qq < 4; ++qq)
                    nxt[qq] = W4[(h0 + qq) * 64 + 8 * (c + 1) + dh];
            }
            const int d = (8 * c + dh) * 4;   // 8 distinct b128 addrs/wave
            #pragma unroll
            for (int p = 0; p < 8; ++p) {
                float4 s = *(const float4*)&sh[(pb + p) * SH_STRIDE + d];
                #pragma unroll
                for (int qq = 0; qq < 4; ++qq)
                    acc[qq][p] += a[qq].x * s.x + a[qq].y * s.y + a[qq].z * s.z + a[qq].w * s.w;
            }
        }

        // exchange-reduce: mask 4, 2, 1; keep hi/lo half by dh bit (static)
        #pragma unroll
        for (int qq = 0; qq < 4; ++qq) {
            #pragma unroll
            for (int j = 0; j < 4; ++j) {
                float lo = acc[qq][j],     olo = __shfl_xor(lo, 4, 64);
                float hi = acc[qq][j + 4], ohi = __shfl_xor(hi, 4, 64);
                acc[qq][j] = (dh & 4) ? (hi + ohi) : (lo + olo);
            }
            #pragma unroll
            for (int j = 0; j < 2; ++j) {
                float lo = acc[qq][j],     olo = __shfl_xor(lo, 2, 64);
                float hi = acc[qq][j + 2], ohi = __shfl_xor(hi, 2, 64);
                acc[qq][j] = (dh & 2) ? (hi + ohi) : (lo + olo);
            }
            {
                float lo = acc[qq][0], olo = __shfl_xor(lo, 1, 64);
                float hi = acc[qq][1], ohi = __shfl_xor(hi, 1, 64);
                acc[qq][0] = (dh & 1) ? (hi + ohi) : (lo + olo);
            }
        }
        const float b0 = attw_b[h0],     b1 = attw_b[h0 + 1];
        const float b2 = attw_b[h0 + 2], b3 = attw_b[h0 + 3];
        const float w0 = attw2_W[h0],     w1 = attw2_W[h0 + 1];
        const float w2 = attw2_W[h0 + 2], w3 = attw2_W[h0 + 3];
        float v = tanhf(acc[0][0] + b0) * w0 + tanhf(acc[1][0] + b1) * w1
                + tanhf(acc[2][0] + b2) * w2 + tanhf(acc[3][0] + b3) * w3;
        lp[(pb + dh) * LP_STRIDE + hp] = v;
    }
    __syncthreads();

    // ---- logit reduce over 32 hp: t < 256 = (p = t>>4, g = t&15) ----
    if (t < 256) {
        const int p = t >> 4, g = t & 15;
        float s = lp[p * LP_STRIDE + 2 * g] + lp[p * LP_STRIDE + 2 * g + 1];
        #pragma unroll
        for (int m = 1; m <= 8; m <<= 1) s += __shfl_xor(s, m, 64);
        if (g == 0) logits[p] = s;
    }
    __syncthreads();

    // ---- softmax over P=16 ----
    if (t < 16) {
        float l = logits[t];
        float m = l;
        for (int mm = 8; mm >= 1; mm >>= 1) m = fmaxf(m, __shfl_xor(m, mm, 64));
        float e = expf(l - m);
        float ssum = e;
        for (int mm = 8; mm >= 1; mm >>= 1) ssum += __shfl_xor(ssum, mm, 64);
        wts[t] = e / ssum;
    }
    __syncthreads();

    // ---- weighted pool -> publish via atomicExch (device coherent point).
    // vdummy consume forces each lane's exch COMPLETION before the barrier,
    // so the arrival atomicAdd below is globally ordered after all data. ----
    if (t < 256) {
        float acc = 0.f;
        #pragma unroll
        for (int p = 0; p < P_; ++p) acc += wts[p] * sh[p * SH_STRIDE + t];
        float old = atomicExch(&gpool[b][pool][t], acc);
        vdummy[t] = old;                   // volatile: store kept, waits vmcnt
    }
    __syncthreads();

    // ---- pair rendezvous (no fences) ----
    if (t == 0) {
        float f = vdummy[0];               // volatile load, value is finite
        int addv = 1 + (int)(f * 0.0f);    // == 1, but not foldable
        sflag = atomicAdd(&gcount[b], addv);
    }
    __syncthreads();
    if (sflag == 0) return;                // first arriver: done
    if (t == 0) atomicExch(&gcount[b], 0); // self-reset for next call

    // ---- winner head: feats from gpool via atomic loads (coherent) ----
    {
        const int pp = t >> 8, d = t & 255;
        feats[pp * 256 + d] = atomicAdd(&gpool[b][pp][d], 0.0f);
    }
    if (t < 128) {
        const int e = ents[b * 2 + (t >> 6)];
        feats[512 + t] = ent_emb[(size_t)e * ED_ + (t & 63)];
    }
    __syncthreads();

    // ---- condensed: 32 groups x 16 lanes, 8 rows/group; per wave-instr
    // 4 rows x 256 B contiguous (16 lines) ----
    {
        const int g = t >> 4, sub = t & 15;
        #pragma unroll
        for (int k = 0; k < 8; ++k) {
            const int r = g + 32 * k;
            const float4* wrow = (const float4*)(cond_W + (size_t)r * FEAT_);
            float4 w[10];
            #pragma unroll
            for (int j = 0; j < 10; ++j) w[j] = wrow[j * 16 + sub];
            float acc = 0.f;
            #pragma unroll
            for (int j = 0; j < 10; ++j) {
                const float* fp = &feats[(j * 16 + sub) * 4];
                acc += w[j].x * fp[0] + w[j].y * fp[1] + w[j].z * fp[2] + w[j].w * fp[3];
            }
            #pragma unroll
            for (int m = 1; m <= 8; m <<= 1) acc += __shfl_xor(acc, m, 64);
            if (sub == 0) part[r] = acc + cond_b[r];
        }
    }
    __syncthreads();

    // ---- tanh + linear head ----
    if (t < 256) {
        const float tv = tanhf(part[t]);
        float v0 = tv * lin_W[t];
        float v1 = tv * lin_W[256 + t];
        #pragma unroll
        for (int m = 32; m >= 1; m >>= 1) {
            v0 += __shfl_xor(v0, m, 64);
            v1 += __shfl_xor(v1, m, 64);
        }
        if ((t & 63) == 0) { r0s[t >> 6] = v0; r1s[t >> 6] = v1; }
    }
    __syncthreads();
    if (t == 0) {
        out[b * 2 + 0] = r0s[0] + r0s[1] + r0s[2] + r0s[3] + lin_b[0];
        out[b * 2 + 1] = r1s[0] + r1s[1] + r1s[2] + r1s[3] + lin_b[1];
    }
}

extern "C" void kernel_launch(void* const* d_in, const int* in_sizes, int n_in,
                              void* d_out, int out_size, void* d_ws, size_t ws_size,
                              hipStream_t stream)
{
    const int* x     = (const int*)d_in[0];
    const int* ents  = (const int*)d_in[1];
    const int* spos  = (const int*)d_in[2];
    const int* tpos  = (const int*)d_in[3];
    const float* emb     = (const float*)d_in[4];
    const float* ent_emb = (const float*)d_in[5];
    const float* attw_W  = (const float*)d_in[6];
    const float* attw_b  = (const float*)d_in[7];
    const float* attw2_W = (const float*)d_in[8];
    const float* cond_W  = (const float*)d_in[9];
    const float* cond_b  = (const float*)d_in[10];
    const float* lin_W   = (const float*)d_in[11];
    const float* lin_b   = (const float*)d_in[12];
    float* out = (float*)d_out;   // [B][2] fp32; d_ws deliberately UNUSED

    fused_kernel<<<2 * B_, 512, 0, stream>>>(
        x, ents, spos, tpos, emb, ent_emb, attw_W, attw_b, attw2_W,
        cond_W, cond_b, lin_W, lin_b, out);
}